// Round 3
// baseline (4503.079 us; speedup 1.0000x reference)
//
#include <hip/hip_runtime.h>

// B=16, C=256, L=2048 -> flat A: N=32768 rows x D=256; K=2048 codewords.
// Outputs (f32, concat): quantized[8388608], indices[32768], loss[1].
// vq_loss = 1.25 * mean((q - x)^2).
// Strategy: d(n,k) = ||e_k||^2 - 2 x.e  (||x||^2 argmin-invariant).
// GEMM (-2x).e via split-bf16 3-pass MFMA; rows where runner-up comes within
// D2 of the min are re-scored exactly in fp32 (matches numpy per rounds 1-2).

#define ZE_CL   (256 * 2048)
#define NROWS   32768
#define KC      2048
#define DD      256
#define IDX_OFF 8388608
#define LOSS_OFF (8388608 + 32768)
#define D2 8e-3f   // margin: flag if |cand - min| < D2 (>= 2x worst split error)

typedef __bf16 bf16x4 __attribute__((ext_vector_type(4)));
typedef __bf16 bf16x8 __attribute__((ext_vector_type(8)));
typedef float  f32x4  __attribute__((ext_vector_type(4)));

// ws layout (bytes)
#define EN_OFF  0u
#define EH_OFF  8192u
#define EL_OFF  (8192u + 1048576u)
#define AH_OFF  (EL_OFF + 1048576u)
#define AL_OFF  (AH_OFF + 16777216u)
#define CNT_OFF (AL_OFF + 16777216u)
#define LST_OFF (CNT_OFF + 8u)
#define WS_NEED (LST_OFF + 131072u)

static __device__ inline bf16x8 ld8(const __bf16* p) {
    bf16x4 a = *(const bf16x4*)p;
    bf16x4 b = *(const bf16x4*)(p + 4);
    return __builtin_shufflevector(a, b, 0, 1, 2, 3, 4, 5, 6, 7);
}
static __device__ inline void st8(__bf16* p, bf16x8 v) {
    *(bf16x4*)p       = __builtin_shufflevector(v, v, 0, 1, 2, 3);
    *(bf16x4*)(p + 4) = __builtin_shufflevector(v, v, 4, 5, 6, 7);
}

// ---------------- codeword squared norms ----------------
__global__ void vq_enorm(const float* __restrict__ emb, float* __restrict__ enorm) {
    int k = blockIdx.x * blockDim.x + threadIdx.x;
    if (k >= KC) return;
    const float4* e4 = (const float4*)(emb + (size_t)k * DD);
    float s = 0.f;
#pragma unroll
    for (int i = 0; i < DD / 4; ++i) {
        float4 v = e4[i];
        s += v.x * v.x + v.y * v.y + v.z * v.z + v.w * v.w;
    }
    enorm[k] = s;
}

// ---------------- emb -> bf16 hi/lo split ----------------
__global__ void vq_split_emb(const float* __restrict__ emb,
                             __bf16* __restrict__ Eh, __bf16* __restrict__ El) {
    int g = blockIdx.x * 256 + threadIdx.x;      // float4 index, 131072 total
    float4 v = ((const float4*)emb)[g];
    bf16x4 h, l;
    h[0] = (__bf16)v.x; l[0] = (__bf16)(v.x - (float)h[0]);
    h[1] = (__bf16)v.y; l[1] = (__bf16)(v.y - (float)h[1]);
    h[2] = (__bf16)v.z; l[2] = (__bf16)(v.z - (float)h[2]);
    h[3] = (__bf16)v.w; l[3] = (__bf16)(v.w - (float)h[3]);
    ((bf16x4*)Eh)[g] = h;
    ((bf16x4*)El)[g] = l;
}

// ---------------- z_e -> flat fp32 A (into out Q region) + (-2x) bf16 split ----
__global__ void vq_transpose_split(const float* __restrict__ ze, float* __restrict__ A,
                                   __bf16* __restrict__ Ah, __bf16* __restrict__ Al) {
    __shared__ float T[16 * 272];
    int tid = threadIdx.x;
    int m  = blockIdx.x & 15;
    int lt = blockIdx.x >> 4;
    int l0 = lt * 16;
#pragma unroll
    for (int it = 0; it < 4; ++it) {
        int p   = tid + it * 256;
        int b   = p >> 6;
        int clo = (p >> 2) & 15;
        int l4  = p & 3;
        const float* g = ze + (size_t)b * ZE_CL + (size_t)(m * 16 + clo) * 2048 + l0 + 4 * l4;
        float4 v = *(const float4*)g;
        int jp = 17 * clo + b;
        T[(4 * l4 + 0) * 272 + jp] = v.x;
        T[(4 * l4 + 1) * 272 + jp] = v.y;
        T[(4 * l4 + 2) * 272 + jp] = v.z;
        T[(4 * l4 + 3) * 272 + jp] = v.w;
    }
    __syncthreads();
#pragma unroll
    for (int it = 0; it < 4; ++it) {
        int p  = tid + it * 256;
        int ll = p >> 6;
        int c4 = p & 63;
        int j0 = 4 * c4;
        int base = ll * 272 + 17 * (j0 >> 4) + (j0 & 15);
        float4 v;
        v.x = T[base + 0]; v.y = T[base + 1]; v.z = T[base + 2]; v.w = T[base + 3];
        int n = (l0 + ll) * 16 + m;
        *(float4*)(A + (size_t)n * DD + j0) = v;
        if (Ah) {
            float a0 = -2.f * v.x, a1 = -2.f * v.y, a2 = -2.f * v.z, a3 = -2.f * v.w;
            bf16x4 h, l;
            h[0] = (__bf16)a0; l[0] = (__bf16)(a0 - (float)h[0]);
            h[1] = (__bf16)a1; l[1] = (__bf16)(a1 - (float)h[1]);
            h[2] = (__bf16)a2; l[2] = (__bf16)(a2 - (float)h[2]);
            h[3] = (__bf16)a3; l[3] = (__bf16)(a3 - (float)h[3]);
            *(bf16x4*)(Ah + (size_t)n * DD + j0) = h;
            *(bf16x4*)(Al + (size_t)n * DD + j0) = l;
        }
    }
}

// ---------------- MFMA distance + argmin + margin flags ----------------
// 512 blocks x 256 thr (4 waves). Block: 64 rows, N-tile 256 cols, K-chunk 32.
// Wave: 64x64 cols via 4x4 frags of mfma_f32_16x16x32_bf16 (verified layouts:
// A[m=lane&15][k=quad*8+j]; C/D row=quad*4+reg, col=lane&15).
__global__ __launch_bounds__(256, 2) void vq_main_mfma(
    const __bf16* __restrict__ Ah, const __bf16* __restrict__ Al,
    const __bf16* __restrict__ Eh, const __bf16* __restrict__ El,
    const float* __restrict__ enorm, float* out,
    int* __restrict__ rcount, int* __restrict__ rlist)
{
    __shared__ __bf16 sAh[64 * 36], sAl[64 * 36];
    __shared__ __bf16 sBh[256 * 36], sBl[256 * 36];
    __shared__ float  sEn[256];
    __shared__ float  sRv[64 * 4];
    __shared__ int    sRi[64 * 4];

    int tid  = threadIdx.x;
    int n0   = blockIdx.x * 64;
    int wv   = tid >> 6;
    int lane = tid & 63;
    int l15  = lane & 15;
    int quad = lane >> 4;

    float v1[16]; int i1[16]; unsigned fl = 0;
#pragma unroll
    for (int s = 0; s < 16; ++s) { v1[s] = 3.4e38f; i1[s] = 0; }

    for (int nt = 0; nt < 8; ++nt) {
        int ncol0 = nt * 256;
        f32x4 acc[4][4];
#pragma unroll
        for (int a = 0; a < 4; ++a)
#pragma unroll
            for (int b = 0; b < 4; ++b) acc[a][b] = (f32x4){0.f, 0.f, 0.f, 0.f};

        for (int ch = 0; ch < 8; ++ch) {
            int kb = ch * 32;
            __syncthreads();
            {   // stage A hi/lo: 64 rows x 32 k
                int row = tid >> 2, c = tid & 3;
                const __bf16* pH = Ah + (size_t)(n0 + row) * DD + kb + c * 8;
                const __bf16* pL = Al + (size_t)(n0 + row) * DD + kb + c * 8;
                int d = row * 36 + c * 8;
                st8(sAh + d, *(const bf16x8*)pH);
                st8(sAl + d, *(const bf16x8*)pL);
            }
            {   // stage B hi/lo: 256 codewords x 32 k
                const __bf16* pH = Eh + (size_t)(ncol0 + tid) * DD + kb;
                const __bf16* pL = El + (size_t)(ncol0 + tid) * DD + kb;
                int d = tid * 36;
#pragma unroll
                for (int c = 0; c < 4; ++c) {
                    st8(sBh + d + c * 8, *(const bf16x8*)(pH + c * 8));
                    st8(sBl + d + c * 8, *(const bf16x8*)(pL + c * 8));
                }
            }
            if (ch == 0) sEn[tid] = enorm[ncol0 + tid];
            __syncthreads();

            bf16x8 ah[4], al[4], bh[4], bl[4];
#pragma unroll
            for (int mi = 0; mi < 4; ++mi) {
                int o = (mi * 16 + l15) * 36 + quad * 8;
                ah[mi] = ld8(sAh + o);
                al[mi] = ld8(sAl + o);
            }
#pragma unroll
            for (int nj = 0; nj < 4; ++nj) {
                int o = (wv * 64 + nj * 16 + l15) * 36 + quad * 8;
                bh[nj] = ld8(sBh + o);
                bl[nj] = ld8(sBl + o);
            }
#pragma unroll
            for (int mi = 0; mi < 4; ++mi)
#pragma unroll
                for (int nj = 0; nj < 4; ++nj)
                    acc[mi][nj] = __builtin_amdgcn_mfma_f32_16x16x32_bf16(ah[mi], bh[nj], acc[mi][nj], 0, 0, 0);
#pragma unroll
            for (int mi = 0; mi < 4; ++mi)
#pragma unroll
                for (int nj = 0; nj < 4; ++nj)
                    acc[mi][nj] = __builtin_amdgcn_mfma_f32_16x16x32_bf16(ah[mi], bl[nj], acc[mi][nj], 0, 0, 0);
#pragma unroll
            for (int mi = 0; mi < 4; ++mi)
#pragma unroll
                for (int nj = 0; nj < 4; ++nj)
                    acc[mi][nj] = __builtin_amdgcn_mfma_f32_16x16x32_bf16(al[mi], bh[nj], acc[mi][nj], 0, 0, 0);
        }
        // fold N-tile into running argmin + margin flags
#pragma unroll
        for (int nj = 0; nj < 4; ++nj) {
            int cl = wv * 64 + nj * 16 + l15;
            float en = sEn[cl];
            int kidx = ncol0 + cl;
#pragma unroll
            for (int mi = 0; mi < 4; ++mi)
#pragma unroll
                for (int r = 0; r < 4; ++r) {
                    float d = acc[mi][nj][r] + en;
                    int slot = mi * 4 + r;
                    if (fabsf(d - v1[slot]) < D2) fl |= (1u << slot);
                    if (d < v1[slot]) { v1[slot] = d; i1[slot] = kidx; }
                }
        }
    }

    // cross-lane reduce: rows live in 16-lane groups (fixed quad); xor 1,2,4,8
#pragma unroll
    for (int slot = 0; slot < 16; ++slot) {
        float v = v1[slot];
        int ix = (i1[slot] << 1) | ((fl >> slot) & 1);
#pragma unroll
        for (int m = 1; m < 16; m <<= 1) {
            float vo = __shfl_xor(v, m, 64);
            int io = __shfl_xor(ix, m, 64);
            int nf = ((ix | io) & 1) | (fabsf(v - vo) < D2 ? 1 : 0);
            if (vo < v) { v = vo; ix = io; }
            ix = (ix & ~1) | nf;
        }
        if (l15 == 0) {
            int row = (slot >> 2) * 16 + quad * 4 + (slot & 3);
            sRv[row * 4 + wv] = v;
            sRi[row * 4 + wv] = ix;
        }
    }
    __syncthreads();
    if (tid < 64) {
        float v = sRv[tid * 4]; int ix = sRi[tid * 4];
#pragma unroll
        for (int w2 = 1; w2 < 4; ++w2) {
            float vo = sRv[tid * 4 + w2]; int io = sRi[tid * 4 + w2];
            int nf = ((ix | io) & 1) | (fabsf(v - vo) < D2 ? 1 : 0);
            if (vo < v) { v = vo; ix = io; }
            ix = (ix & ~1) | nf;
        }
        out[IDX_OFF + n0 + tid] = (float)(ix >> 1);
        if (ix & 1) { int p = atomicAdd(rcount, 1); rlist[p] = n0 + tid; }
    }
}

// ---------------- exact fp32 rescore of flagged rows ----------------
__global__ void vq_rescore(const float* __restrict__ emb, const float* __restrict__ enorm,
                           float* out, const int* __restrict__ rcount,
                           const int* __restrict__ rlist) {
    __shared__ float sX[256];
    __shared__ float sV[256];
    __shared__ int   sK[256];
    int cnt = *rcount;
    for (int li = blockIdx.x; li < cnt; li += gridDim.x) {
        int row = rlist[li];
        __syncthreads();
        sX[threadIdx.x] = out[(size_t)row * DD + threadIdx.x];
        __syncthreads();
        float bv = 3.4e38f; int bk = 0;
        for (int jj = 0; jj < 8; ++jj) {
            int k = jj * 256 + threadIdx.x;   // ascending per thread: '<' keeps first
            const float4* e4 = (const float4*)(emb + (size_t)k * DD);
            float dot = 0.f;
#pragma unroll 8
            for (int d4 = 0; d4 < 64; ++d4) {
                float4 e = e4[d4];
                float4 x = *(const float4*)(sX + d4 * 4);
                dot += x.x * e.x + x.y * e.y + x.z * e.z + x.w * e.w;
            }
            float s = enorm[k] - 2.f * dot;
            if (s < bv) { bv = s; bk = k; }
        }
        sV[threadIdx.x] = bv; sK[threadIdx.x] = bk;
        __syncthreads();
        if (threadIdx.x == 0) {
            float v = sV[0]; int k = sK[0];
            for (int t = 1; t < 256; ++t)
                if (sV[t] < v || (sV[t] == v && sK[t] < k)) { v = sV[t]; k = sK[t]; }
            out[IDX_OFF + row] = (float)k;
        }
    }
}

// ---------------- quantize gather + loss ----------------
__global__ void vq_epilogue(const float* __restrict__ emb, float* out) {
    __shared__ int sIdx[64];
    __shared__ float wsum[4];
    int tid = threadIdx.x;
    int n0 = blockIdx.x * 64;
    if (tid < 64) sIdx[tid] = (int)out[IDX_OFF + n0 + tid];
    __syncthreads();
    float lacc = 0.f;
#pragma unroll
    for (int it = 0; it < 16; ++it) {
        int p = tid + it * 256;
        int r = p >> 6;
        int c4 = p & 63;
        int k = sIdx[r];
        size_t off = (size_t)(n0 + r) * DD + 4 * c4;
        float4 q = *(const float4*)(emb + (size_t)k * DD + 4 * c4);
        float4 a = *(const float4*)(out + off);   // fp32 x, read-before-write
        float dx = q.x - a.x, dy = q.y - a.y, dz = q.z - a.z, dw = q.w - a.w;
        lacc += dx * dx + dy * dy + dz * dz + dw * dw;
        *(float4*)(out + off) = q;
    }
#pragma unroll
    for (int off = 32; off > 0; off >>= 1) lacc += __shfl_down(lacc, off, 64);
    if ((tid & 63) == 0) wsum[tid >> 6] = lacc;
    __syncthreads();
    if (tid == 0) {
        float bs = wsum[0] + wsum[1] + wsum[2] + wsum[3];
        atomicAdd(out + LOSS_OFF, bs * (1.25f / 8388608.0f));
    }
}

// ---------------- fallback fp32 main (round-2, used only if ws too small) ----
__global__ __launch_bounds__(256, 2) void vq_main_f32(const float* __restrict__ emb,
                                                      const float* __restrict__ enorm,
                                                      float* out) {
    const int SA = 68, SE = 68;
    __shared__ float smem[64 * 68 + 64 * 68];
    __shared__ int   sIdx[64];
    __shared__ float wsum[4];
    float* sA = smem;
    float* sEb = smem + 64 * SA;
    float* redv = sEb;
    int*   redi = (int*)(sEb + 64 * 16);
    int tid = threadIdx.x;
    int n0 = blockIdx.x * 64;
    int rg = tid & 15;
    int kg = tid >> 4;
    float minv[4]; int mini[4];
#pragma unroll
    for (int i = 0; i < 4; ++i) { minv[i] = 3.4e38f; mini[i] = 0; }
    const float* A = out;
    for (int kt = 0; kt < KC / 64; ++kt) {
        int k0 = kt * 64;
        float acc[4][4];
#pragma unroll
        for (int i = 0; i < 4; ++i)
#pragma unroll
            for (int j = 0; j < 4; ++j) acc[i][j] = 0.f;
        for (int dc = 0; dc < 4; ++dc) {
            int d0 = dc * 64;
            __syncthreads();
#pragma unroll
            for (int it = 0; it < 4; ++it) {
                int p = tid + it * 256, r = p >> 4, c4 = p & 15;
                *(float4*)(sA + r * SA + 4 * c4) =
                    *(const float4*)(A + (size_t)(n0 + r) * DD + d0 + 4 * c4);
            }
#pragma unroll
            for (int it = 0; it < 4; ++it) {
                int p = tid + it * 256, r = p >> 4, c4 = p & 15;
                *(float4*)(sEb + r * SE + 4 * c4) =
                    *(const float4*)(emb + (size_t)(k0 + r) * DD + d0 + 4 * c4);
            }
            __syncthreads();
#pragma unroll
            for (int d4 = 0; d4 < 16; ++d4) {
                float4 av[4], ev[4];
#pragma unroll
                for (int i = 0; i < 4; ++i) av[i] = *(const float4*)(sA + (rg + 16 * i) * SA + 4 * d4);
#pragma unroll
                for (int j = 0; j < 4; ++j) ev[j] = *(const float4*)(sEb + (kg + 16 * j) * SE + 4 * d4);
#pragma unroll
                for (int i = 0; i < 4; ++i)
#pragma unroll
                    for (int j = 0; j < 4; ++j)
                        acc[i][j] += av[i].x * ev[j].x + av[i].y * ev[j].y +
                                     av[i].z * ev[j].z + av[i].w * ev[j].w;
            }
        }
#pragma unroll
        for (int j = 0; j < 4; ++j) {
            int k = k0 + kg + 16 * j;
            float en = enorm[k];
#pragma unroll
            for (int i = 0; i < 4; ++i) {
                float s = en - 2.f * acc[i][j];
                if (s < minv[i]) { minv[i] = s; mini[i] = k; }
            }
        }
    }
    __syncthreads();
#pragma unroll
    for (int i = 0; i < 4; ++i) {
        int r = rg + 16 * i;
        redv[r * 16 + kg] = minv[i];
        redi[r * 16 + kg] = mini[i];
    }
    __syncthreads();
    if (tid < 64) {
        float bv = redv[tid * 16]; int bi = redi[tid * 16];
        for (int t = 1; t < 16; ++t) {
            float v = redv[tid * 16 + t]; int ii = redi[tid * 16 + t];
            if (v < bv || (v == bv && ii < bi)) { bv = v; bi = ii; }
        }
        sIdx[tid] = bi;
        out[IDX_OFF + n0 + tid] = (float)bi;
    }
    __syncthreads();
    float lacc = 0.f;
#pragma unroll
    for (int it = 0; it < 16; ++it) {
        int p = tid + it * 256, r = p >> 6, c4 = p & 63;
        int k = sIdx[r];
        size_t off = (size_t)(n0 + r) * DD + 4 * c4;
        float4 q = *(const float4*)(emb + (size_t)k * DD + 4 * c4);
        float4 a = *(const float4*)(out + off);
        float dx = q.x - a.x, dy = q.y - a.y, dz = q.z - a.z, dw = q.w - a.w;
        lacc += dx * dx + dy * dy + dz * dz + dw * dw;
        *(float4*)(out + off) = q;
    }
#pragma unroll
    for (int off = 32; off > 0; off >>= 1) lacc += __shfl_down(lacc, off, 64);
    if ((tid & 63) == 0) wsum[tid >> 6] = lacc;
    __syncthreads();
    if (tid == 0) {
        float bs = wsum[0] + wsum[1] + wsum[2] + wsum[3];
        atomicAdd(out + LOSS_OFF, bs * (1.25f / 8388608.0f));
    }
}

extern "C" void kernel_launch(void* const* d_in, const int* in_sizes, int n_in,
                              void* d_out, int out_size, void* d_ws, size_t ws_size,
                              hipStream_t stream) {
    (void)in_sizes; (void)n_in; (void)out_size;
    const float* ze  = (const float*)d_in[0];
    const float* emb = (const float*)d_in[1];
    float* out = (float*)d_out;
    char*  ws  = (char*)d_ws;
    float* enorm = (float*)(ws + EN_OFF);

    hipMemsetAsync((char*)d_out + (size_t)LOSS_OFF * 4, 0, 4, stream);
    vq_enorm<<<KC / 256, 256, 0, stream>>>(emb, enorm);

    if (ws_size >= (size_t)WS_NEED) {
        __bf16* Eh = (__bf16*)(ws + EH_OFF);
        __bf16* El = (__bf16*)(ws + EL_OFF);
        __bf16* Ah = (__bf16*)(ws + AH_OFF);
        __bf16* Al = (__bf16*)(ws + AL_OFF);
        int* rcount = (int*)(ws + CNT_OFF);
        int* rlist  = (int*)(ws + LST_OFF);
        hipMemsetAsync(ws + CNT_OFF, 0, 8, stream);
        vq_split_emb<<<512, 256, 0, stream>>>(emb, Eh, El);
        vq_transpose_split<<<2048, 256, 0, stream>>>(ze, out, Ah, Al);
        vq_main_mfma<<<NROWS / 64, 256, 0, stream>>>(Ah, Al, Eh, El, enorm, out, rcount, rlist);
        vq_rescore<<<128, 256, 0, stream>>>(emb, enorm, out, rcount, rlist);
        vq_epilogue<<<NROWS / 64, 256, 0, stream>>>(emb, out);
    } else {
        vq_transpose_split<<<2048, 256, 0, stream>>>(ze, out, (__bf16*)0, (__bf16*)0);
        vq_main_f32<<<NROWS / 64, 256, 0, stream>>>(emb, enorm, out);
    }
}

// Round 4
// 366.740 us; speedup vs baseline: 12.2787x; 12.2787x over previous
//
#include <hip/hip_runtime.h>

// B=16, C=256, L=2048 -> flat A: N=32768 rows x D=256; K=2048 codewords.
// Outputs (f32, concat): quantized[8388608], indices[32768], loss[1].
// vq_loss = 1.25 * mean((q - x)^2).
// d(n,k) = ||e_k||^2 - 2 x.e  (||x||^2 argmin-invariant).
// GEMM (-2x).e via split-bf16 3-pass MFMA (err rms ~3e-4). TRUE top-2 gap
// tracking: rows with (min2-min1) < D2 are re-scored exactly in fp32.

#define ZE_CL   (256 * 2048)
#define NROWS   32768
#define KC      2048
#define DD      256
#define IDX_OFF 8388608
#define LOSS_OFF (8388608 + 32768)
#define D2 8e-3f   // runner-up gap margin (>= 2x worst split error, ~25 sigma)

typedef __bf16 bf16x4 __attribute__((ext_vector_type(4)));
typedef __bf16 bf16x8 __attribute__((ext_vector_type(8)));
typedef float  f32x4  __attribute__((ext_vector_type(4)));

// ws layout (bytes)
#define EN_OFF  0u
#define EH_OFF  8192u
#define EL_OFF  (8192u + 1048576u)
#define AH_OFF  (EL_OFF + 1048576u)
#define AL_OFF  (AH_OFF + 16777216u)
#define CNT_OFF (AL_OFF + 16777216u)
#define LST_OFF (CNT_OFF + 8u)
#define WS_NEED (LST_OFF + 131072u)

static __device__ inline bf16x8 ld8(const __bf16* p) {
    bf16x4 a = *(const bf16x4*)p;
    bf16x4 b = *(const bf16x4*)(p + 4);
    return __builtin_shufflevector(a, b, 0, 1, 2, 3, 4, 5, 6, 7);
}
static __device__ inline void st8(__bf16* p, bf16x8 v) {
    *(bf16x4*)p       = __builtin_shufflevector(v, v, 0, 1, 2, 3);
    *(bf16x4*)(p + 4) = __builtin_shufflevector(v, v, 4, 5, 6, 7);
}

// ---------------- codeword squared norms ----------------
__global__ void vq_enorm(const float* __restrict__ emb, float* __restrict__ enorm) {
    int k = blockIdx.x * blockDim.x + threadIdx.x;
    if (k >= KC) return;
    const float4* e4 = (const float4*)(emb + (size_t)k * DD);
    float s = 0.f;
#pragma unroll
    for (int i = 0; i < DD / 4; ++i) {
        float4 v = e4[i];
        s += v.x * v.x + v.y * v.y + v.z * v.z + v.w * v.w;
    }
    enorm[k] = s;
}

// ---------------- emb -> bf16 hi/lo split ----------------
__global__ void vq_split_emb(const float* __restrict__ emb,
                             __bf16* __restrict__ Eh, __bf16* __restrict__ El) {
    int g = blockIdx.x * 256 + threadIdx.x;      // float4 index, 131072 total
    float4 v = ((const float4*)emb)[g];
    bf16x4 h, l;
    h[0] = (__bf16)v.x; l[0] = (__bf16)(v.x - (float)h[0]);
    h[1] = (__bf16)v.y; l[1] = (__bf16)(v.y - (float)h[1]);
    h[2] = (__bf16)v.z; l[2] = (__bf16)(v.z - (float)h[2]);
    h[3] = (__bf16)v.w; l[3] = (__bf16)(v.w - (float)h[3]);
    ((bf16x4*)Eh)[g] = h;
    ((bf16x4*)El)[g] = l;
}

// ---------------- z_e -> flat fp32 A (into out Q region) + (-2x) bf16 split ----
__global__ void vq_transpose_split(const float* __restrict__ ze, float* __restrict__ A,
                                   __bf16* __restrict__ Ah, __bf16* __restrict__ Al) {
    __shared__ float T[16 * 272];
    int tid = threadIdx.x;
    int m  = blockIdx.x & 15;
    int lt = blockIdx.x >> 4;
    int l0 = lt * 16;
#pragma unroll
    for (int it = 0; it < 4; ++it) {
        int p   = tid + it * 256;
        int b   = p >> 6;
        int clo = (p >> 2) & 15;
        int l4  = p & 3;
        const float* g = ze + (size_t)b * ZE_CL + (size_t)(m * 16 + clo) * 2048 + l0 + 4 * l4;
        float4 v = *(const float4*)g;
        int jp = 17 * clo + b;
        T[(4 * l4 + 0) * 272 + jp] = v.x;
        T[(4 * l4 + 1) * 272 + jp] = v.y;
        T[(4 * l4 + 2) * 272 + jp] = v.z;
        T[(4 * l4 + 3) * 272 + jp] = v.w;
    }
    __syncthreads();
#pragma unroll
    for (int it = 0; it < 4; ++it) {
        int p  = tid + it * 256;
        int ll = p >> 6;
        int c4 = p & 63;
        int j0 = 4 * c4;
        int base = ll * 272 + 17 * (j0 >> 4) + (j0 & 15);
        float4 v;
        v.x = T[base + 0]; v.y = T[base + 1]; v.z = T[base + 2]; v.w = T[base + 3];
        int n = (l0 + ll) * 16 + m;
        *(float4*)(A + (size_t)n * DD + j0) = v;
        if (Ah) {
            float a0 = -2.f * v.x, a1 = -2.f * v.y, a2 = -2.f * v.z, a3 = -2.f * v.w;
            bf16x4 h, l;
            h[0] = (__bf16)a0; l[0] = (__bf16)(a0 - (float)h[0]);
            h[1] = (__bf16)a1; l[1] = (__bf16)(a1 - (float)h[1]);
            h[2] = (__bf16)a2; l[2] = (__bf16)(a2 - (float)h[2]);
            h[3] = (__bf16)a3; l[3] = (__bf16)(a3 - (float)h[3]);
            *(bf16x4*)(Ah + (size_t)n * DD + j0) = h;
            *(bf16x4*)(Al + (size_t)n * DD + j0) = l;
        }
    }
}

// ---------------- MFMA distance + top-2 argmin ----------------
// 512 blocks x 256 thr (4 waves). Block: 64 rows, N-tile 256 cols, K-chunk 32.
// Wave: 64x64 cols via 4x4 frags of mfma_f32_16x16x32_bf16 (verified layouts:
// A[m=lane&15][k=quad*8+j]; C/D row=quad*4+reg, col=lane&15).
__global__ __launch_bounds__(256, 2) void vq_main_mfma(
    const __bf16* __restrict__ Ah, const __bf16* __restrict__ Al,
    const __bf16* __restrict__ Eh, const __bf16* __restrict__ El,
    const float* __restrict__ enorm, float* out,
    int* __restrict__ rcount, int* __restrict__ rlist)
{
    __shared__ __bf16 sAh[64 * 36], sAl[64 * 36];
    __shared__ __bf16 sBh[256 * 36], sBl[256 * 36];
    __shared__ float  sEn[256];
    __shared__ float  sRv[64 * 4];
    __shared__ float  sR2[64 * 4];
    __shared__ int    sRi[64 * 4];

    int tid  = threadIdx.x;
    int n0   = blockIdx.x * 64;
    int wv   = tid >> 6;
    int lane = tid & 63;
    int l15  = lane & 15;
    int quad = lane >> 4;

    float v1[16], v2[16]; int i1[16];
#pragma unroll
    for (int s = 0; s < 16; ++s) { v1[s] = 3.4e38f; v2[s] = 3.4e38f; i1[s] = 0; }

    for (int nt = 0; nt < 8; ++nt) {
        int ncol0 = nt * 256;
        f32x4 acc[4][4];
#pragma unroll
        for (int a = 0; a < 4; ++a)
#pragma unroll
            for (int b = 0; b < 4; ++b) acc[a][b] = (f32x4){0.f, 0.f, 0.f, 0.f};

        for (int ch = 0; ch < 8; ++ch) {
            int kb = ch * 32;
            __syncthreads();
            {   // stage A hi/lo: 64 rows x 32 k
                int row = tid >> 2, c = tid & 3;
                const __bf16* pH = Ah + (size_t)(n0 + row) * DD + kb + c * 8;
                const __bf16* pL = Al + (size_t)(n0 + row) * DD + kb + c * 8;
                int d = row * 36 + c * 8;
                st8(sAh + d, *(const bf16x8*)pH);
                st8(sAl + d, *(const bf16x8*)pL);
            }
            {   // stage B hi/lo: 256 codewords x 32 k
                const __bf16* pH = Eh + (size_t)(ncol0 + tid) * DD + kb;
                const __bf16* pL = El + (size_t)(ncol0 + tid) * DD + kb;
                int d = tid * 36;
#pragma unroll
                for (int c = 0; c < 4; ++c) {
                    st8(sBh + d + c * 8, *(const bf16x8*)(pH + c * 8));
                    st8(sBl + d + c * 8, *(const bf16x8*)(pL + c * 8));
                }
            }
            if (ch == 0) sEn[tid] = enorm[ncol0 + tid];
            __syncthreads();

            bf16x8 ah[4], al[4], bh[4], bl[4];
#pragma unroll
            for (int mi = 0; mi < 4; ++mi) {
                int o = (mi * 16 + l15) * 36 + quad * 8;
                ah[mi] = ld8(sAh + o);
                al[mi] = ld8(sAl + o);
            }
#pragma unroll
            for (int nj = 0; nj < 4; ++nj) {
                int o = (wv * 64 + nj * 16 + l15) * 36 + quad * 8;
                bh[nj] = ld8(sBh + o);
                bl[nj] = ld8(sBl + o);
            }
#pragma unroll
            for (int mi = 0; mi < 4; ++mi)
#pragma unroll
                for (int nj = 0; nj < 4; ++nj)
                    acc[mi][nj] = __builtin_amdgcn_mfma_f32_16x16x32_bf16(ah[mi], bh[nj], acc[mi][nj], 0, 0, 0);
#pragma unroll
            for (int mi = 0; mi < 4; ++mi)
#pragma unroll
                for (int nj = 0; nj < 4; ++nj)
                    acc[mi][nj] = __builtin_amdgcn_mfma_f32_16x16x32_bf16(ah[mi], bl[nj], acc[mi][nj], 0, 0, 0);
#pragma unroll
            for (int mi = 0; mi < 4; ++mi)
#pragma unroll
                for (int nj = 0; nj < 4; ++nj)
                    acc[mi][nj] = __builtin_amdgcn_mfma_f32_16x16x32_bf16(al[mi], bh[nj], acc[mi][nj], 0, 0, 0);
        }
        // fold N-tile into running top-2 (branchless)
#pragma unroll
        for (int nj = 0; nj < 4; ++nj) {
            int cl = wv * 64 + nj * 16 + l15;
            float en = sEn[cl];
            int kidx = ncol0 + cl;
#pragma unroll
            for (int mi = 0; mi < 4; ++mi)
#pragma unroll
                for (int r = 0; r < 4; ++r) {
                    float d = acc[mi][nj][r] + en;
                    int slot = mi * 4 + r;
                    float nv2 = fminf(v2[slot], fmaxf(v1[slot], d));
                    if (d < v1[slot]) i1[slot] = kidx;
                    v1[slot] = fminf(v1[slot], d);
                    v2[slot] = nv2;
                }
        }
    }

    // cross-lane top-2 merge: rows live in 16-lane groups (fixed quad); xor 1,2,4,8
#pragma unroll
    for (int slot = 0; slot < 16; ++slot) {
        float a1 = v1[slot], a2 = v2[slot];
        int ai = i1[slot];
#pragma unroll
        for (int m = 1; m < 16; m <<= 1) {
            float b1 = __shfl_xor(a1, m, 64);
            float b2 = __shfl_xor(a2, m, 64);
            int bi = __shfl_xor(ai, m, 64);
            float n2 = fminf(fminf(a2, b2), fmaxf(a1, b1));
            if (b1 < a1) ai = bi;
            a1 = fminf(a1, b1);
            a2 = n2;
        }
        if (l15 == 0) {
            int row = (slot >> 2) * 16 + quad * 4 + (slot & 3);
            sRv[row * 4 + wv] = a1;
            sR2[row * 4 + wv] = a2;
            sRi[row * 4 + wv] = ai;
        }
    }
    __syncthreads();
    if (tid < 64) {
        float a1 = sRv[tid * 4], a2 = sR2[tid * 4];
        int ai = sRi[tid * 4];
#pragma unroll
        for (int w2 = 1; w2 < 4; ++w2) {
            float b1 = sRv[tid * 4 + w2], b2 = sR2[tid * 4 + w2];
            int bi = sRi[tid * 4 + w2];
            float n2 = fminf(fminf(a2, b2), fmaxf(a1, b1));
            if (b1 < a1) ai = bi;
            a1 = fminf(a1, b1);
            a2 = n2;
        }
        out[IDX_OFF + n0 + tid] = (float)ai;
        if (a2 - a1 < D2) {   // true runner-up gap inside error margin -> exact rescore
            int p = atomicAdd(rcount, 1);
            rlist[p] = n0 + tid;
        }
    }
}

// ---------------- exact fp32 rescore of flagged rows ----------------
__global__ void vq_rescore(const float* __restrict__ emb, const float* __restrict__ enorm,
                           float* out, const int* __restrict__ rcount,
                           const int* __restrict__ rlist) {
    __shared__ float sX[256];
    __shared__ float sV[256];
    __shared__ int   sK[256];
    int cnt = *rcount;
    int tid = threadIdx.x;
    for (int li = blockIdx.x; li < cnt; li += gridDim.x) {
        int row = rlist[li];
        __syncthreads();
        sX[tid] = out[(size_t)row * DD + tid];
        __syncthreads();
        float bv = 3.4e38f; int bk = 0;
        for (int jj = 0; jj < 8; ++jj) {
            int k = jj * 256 + tid;   // ascending per thread: '<' keeps first
            const float4* e4 = (const float4*)(emb + (size_t)k * DD);
            float dot = 0.f;
#pragma unroll 8
            for (int d4 = 0; d4 < 64; ++d4) {
                float4 e = e4[d4];
                float4 x = *(const float4*)(sX + d4 * 4);
                dot += x.x * e.x + x.y * e.y + x.z * e.z + x.w * e.w;
            }
            float s = enorm[k] - 2.f * dot;
            if (s < bv) { bv = s; bk = k; }
        }
        sV[tid] = bv; sK[tid] = bk;
        __syncthreads();
#pragma unroll
        for (int s = 128; s > 0; s >>= 1) {
            if (tid < s) {
                float vo = sV[tid + s]; int ko = sK[tid + s];
                if (vo < sV[tid] || (vo == sV[tid] && ko < sK[tid])) { sV[tid] = vo; sK[tid] = ko; }
            }
            __syncthreads();
        }
        if (tid == 0) out[IDX_OFF + row] = (float)sK[0];
    }
}

// ---------------- quantize gather + loss ----------------
__global__ void vq_epilogue(const float* __restrict__ emb, float* out) {
    __shared__ int sIdx[64];
    __shared__ float wsum[4];
    int tid = threadIdx.x;
    int n0 = blockIdx.x * 64;
    if (tid < 64) sIdx[tid] = (int)out[IDX_OFF + n0 + tid];
    __syncthreads();
    float lacc = 0.f;
#pragma unroll
    for (int it = 0; it < 16; ++it) {
        int p = tid + it * 256;
        int r = p >> 6;
        int c4 = p & 63;
        int k = sIdx[r];
        size_t off = (size_t)(n0 + r) * DD + 4 * c4;
        float4 q = *(const float4*)(emb + (size_t)k * DD + 4 * c4);
        float4 a = *(const float4*)(out + off);   // fp32 x, read-before-write
        float dx = q.x - a.x, dy = q.y - a.y, dz = q.z - a.z, dw = q.w - a.w;
        lacc += dx * dx + dy * dy + dz * dz + dw * dw;
        *(float4*)(out + off) = q;
    }
#pragma unroll
    for (int off = 32; off > 0; off >>= 1) lacc += __shfl_down(lacc, off, 64);
    if ((tid & 63) == 0) wsum[tid >> 6] = lacc;
    __syncthreads();
    if (tid == 0) {
        float bs = wsum[0] + wsum[1] + wsum[2] + wsum[3];
        atomicAdd(out + LOSS_OFF, bs * (1.25f / 8388608.0f));
    }
}

// ---------------- fallback fp32 main (only if ws too small) ----------------
__global__ __launch_bounds__(256, 2) void vq_main_f32(const float* __restrict__ emb,
                                                      const float* __restrict__ enorm,
                                                      float* out) {
    const int SA = 68, SE = 68;
    __shared__ float smem[64 * 68 + 64 * 68];
    __shared__ int   sIdx[64];
    __shared__ float wsum[4];
    float* sA = smem;
    float* sEb = smem + 64 * SA;
    float* redv = sEb;
    int*   redi = (int*)(sEb + 64 * 16);
    int tid = threadIdx.x;
    int n0 = blockIdx.x * 64;
    int rg = tid & 15;
    int kg = tid >> 4;
    float minv[4]; int mini[4];
#pragma unroll
    for (int i = 0; i < 4; ++i) { minv[i] = 3.4e38f; mini[i] = 0; }
    const float* A = out;
    for (int kt = 0; kt < KC / 64; ++kt) {
        int k0 = kt * 64;
        float acc[4][4];
#pragma unroll
        for (int i = 0; i < 4; ++i)
#pragma unroll
            for (int j = 0; j < 4; ++j) acc[i][j] = 0.f;
        for (int dc = 0; dc < 4; ++dc) {
            int d0 = dc * 64;
            __syncthreads();
#pragma unroll
            for (int it = 0; it < 4; ++it) {
                int p = tid + it * 256, r = p >> 4, c4 = p & 15;
                *(float4*)(sA + r * SA + 4 * c4) =
                    *(const float4*)(A + (size_t)(n0 + r) * DD + d0 + 4 * c4);
            }
#pragma unroll
            for (int it = 0; it < 4; ++it) {
                int p = tid + it * 256, r = p >> 4, c4 = p & 15;
                *(float4*)(sEb + r * SE + 4 * c4) =
                    *(const float4*)(emb + (size_t)(k0 + r) * DD + d0 + 4 * c4);
            }
            __syncthreads();
#pragma unroll
            for (int d4 = 0; d4 < 16; ++d4) {
                float4 av[4], ev[4];
#pragma unroll
                for (int i = 0; i < 4; ++i) av[i] = *(const float4*)(sA + (rg + 16 * i) * SA + 4 * d4);
#pragma unroll
                for (int j = 0; j < 4; ++j) ev[j] = *(const float4*)(sEb + (kg + 16 * j) * SE + 4 * d4);
#pragma unroll
                for (int i = 0; i < 4; ++i)
#pragma unroll
                    for (int j = 0; j < 4; ++j)
                        acc[i][j] += av[i].x * ev[j].x + av[i].y * ev[j].y +
                                     av[i].z * ev[j].z + av[i].w * ev[j].w;
            }
        }
#pragma unroll
        for (int j = 0; j < 4; ++j) {
            int k = k0 + kg + 16 * j;
            float en = enorm[k];
#pragma unroll
            for (int i = 0; i < 4; ++i) {
                float s = en - 2.f * acc[i][j];
                if (s < minv[i]) { minv[i] = s; mini[i] = k; }
            }
        }
    }
    __syncthreads();
#pragma unroll
    for (int i = 0; i < 4; ++i) {
        int r = rg + 16 * i;
        redv[r * 16 + kg] = minv[i];
        redi[r * 16 + kg] = mini[i];
    }
    __syncthreads();
    if (tid < 64) {
        float bv = redv[tid * 16]; int bi = redi[tid * 16];
        for (int t = 1; t < 16; ++t) {
            float v = redv[tid * 16 + t]; int ii = redi[tid * 16 + t];
            if (v < bv || (v == bv && ii < bi)) { bv = v; bi = ii; }
        }
        sIdx[tid] = bi;
        out[IDX_OFF + n0 + tid] = (float)bi;
    }
    __syncthreads();
    float lacc = 0.f;
#pragma unroll
    for (int it = 0; it < 16; ++it) {
        int p = tid + it * 256, r = p >> 6, c4 = p & 63;
        int k = sIdx[r];
        size_t off = (size_t)(n0 + r) * DD + 4 * c4;
        float4 q = *(const float4*)(emb + (size_t)k * DD + 4 * c4);
        float4 a = *(const float4*)(out + off);
        float dx = q.x - a.x, dy = q.y - a.y, dz = q.z - a.z, dw = q.w - a.w;
        lacc += dx * dx + dy * dy + dz * dz + dw * dw;
        *(float4*)(out + off) = q;
    }
#pragma unroll
    for (int off = 32; off > 0; off >>= 1) lacc += __shfl_down(lacc, off, 64);
    if ((tid & 63) == 0) wsum[tid >> 6] = lacc;
    __syncthreads();
    if (tid == 0) {
        float bs = wsum[0] + wsum[1] + wsum[2] + wsum[3];
        atomicAdd(out + LOSS_OFF, bs * (1.25f / 8388608.0f));
    }
}

extern "C" void kernel_launch(void* const* d_in, const int* in_sizes, int n_in,
                              void* d_out, int out_size, void* d_ws, size_t ws_size,
                              hipStream_t stream) {
    (void)in_sizes; (void)n_in; (void)out_size;
    const float* ze  = (const float*)d_in[0];
    const float* emb = (const float*)d_in[1];
    float* out = (float*)d_out;
    char*  ws  = (char*)d_ws;
    float* enorm = (float*)(ws + EN_OFF);

    hipMemsetAsync((char*)d_out + (size_t)LOSS_OFF * 4, 0, 4, stream);
    vq_enorm<<<KC / 256, 256, 0, stream>>>(emb, enorm);

    if (ws_size >= (size_t)WS_NEED) {
        __bf16* Eh = (__bf16*)(ws + EH_OFF);
        __bf16* El = (__bf16*)(ws + EL_OFF);
        __bf16* Ah = (__bf16*)(ws + AH_OFF);
        __bf16* Al = (__bf16*)(ws + AL_OFF);
        int* rcount = (int*)(ws + CNT_OFF);
        int* rlist  = (int*)(ws + LST_OFF);
        hipMemsetAsync(ws + CNT_OFF, 0, 8, stream);
        vq_split_emb<<<512, 256, 0, stream>>>(emb, Eh, El);
        vq_transpose_split<<<2048, 256, 0, stream>>>(ze, out, Ah, Al);
        vq_main_mfma<<<NROWS / 64, 256, 0, stream>>>(Ah, Al, Eh, El, enorm, out, rcount, rlist);
        vq_rescore<<<128, 256, 0, stream>>>(emb, enorm, out, rcount, rlist);
        vq_epilogue<<<NROWS / 64, 256, 0, stream>>>(emb, out);
    } else {
        vq_transpose_split<<<2048, 256, 0, stream>>>(ze, out, (__bf16*)0, (__bf16*)0);
        vq_main_f32<<<NROWS / 64, 256, 0, stream>>>(emb, enorm, out);
    }
}

// Round 5
// 308.219 us; speedup vs baseline: 14.6100x; 1.1899x over previous
//
#include <hip/hip_runtime.h>

// B=16, C=256, L=2048 -> flat A: N=32768 rows x D=256; K=2048 codewords.
// Outputs (f32, concat): quantized[8388608], indices[32768], loss[1].
// d(n,k) = ||e_k||^2 - 2 x.e ; GEMM via split-bf16 3-pass MFMA; rows with
// top-2 gap < D2 skipped in main and finalized exactly (fp32) by rescore.
// Operands pre-swizzled in ws to the MFMA frag image: 16B cell = 8 bf16
// (k-octet), layout [chunk][q=0..3][lane16]*16B -> lane-linear ds/global reads.

#define ZE_CL   (256 * 2048)
#define NROWS   32768
#define KC      2048
#define DD      256
#define IDX_OFF 8388608
#define LOSS_OFF (8388608 + 32768)
#define D2 8e-3f

typedef __bf16 bf16x4 __attribute__((ext_vector_type(4)));
typedef __bf16 bf16x8 __attribute__((ext_vector_type(8)));
typedef float  f32x4  __attribute__((ext_vector_type(4)));

// ws layout (bytes)
#define EN_OFF  0u
#define EH_OFF  8192u
#define EL_OFF  (EH_OFF + 1048576u)
#define AH_OFF  (EL_OFF + 1048576u)
#define AL_OFF  (AH_OFF + 16777216u)
#define CNT_OFF (AL_OFF + 16777216u)
#define LST_OFF (CNT_OFF + 16u)
#define WS_NEED (LST_OFF + 131072u)

static __device__ inline void gld_lds16(const void* g, void* l) {
    __builtin_amdgcn_global_load_lds(
        (const __attribute__((address_space(1))) void*)g,
        (__attribute__((address_space(3))) void*)l, 16, 0, 0);
}

// ---------------- emb -> enorm + swizzled bf16 hi/lo ----------------
// Eh/El image: [t8=col>>8][ch][g=(col>>4)&15][q][c=col&15] 16B cells.
__global__ void vq_prep_emb(const float* __restrict__ emb, float* __restrict__ enorm,
                            __bf16* __restrict__ Eh, __bf16* __restrict__ El) {
    int col = blockIdx.x * 256 + threadIdx.x;
    const float4* src = (const float4*)(emb + (size_t)col * DD);
    int t8 = col >> 8, g = (col >> 4) & 15, c = col & 15;
    float s = 0.f;
#pragma unroll
    for (int ch = 0; ch < 8; ++ch) {
#pragma unroll
        for (int q = 0; q < 4; ++q) {
            float4 v0 = src[ch * 8 + q * 2];
            float4 v1 = src[ch * 8 + q * 2 + 1];
            float f[8] = {v0.x, v0.y, v0.z, v0.w, v1.x, v1.y, v1.z, v1.w};
            bf16x8 h, l;
#pragma unroll
            for (int j = 0; j < 8; ++j) {
                h[j] = (__bf16)f[j];
                l[j] = (__bf16)(f[j] - (float)h[j]);
                s += f[j] * f[j];
            }
            size_t off = ((size_t)(t8 * 8 + ch) * 16384) + (size_t)(g * 1024 + q * 256 + c * 16);
            *(bf16x8*)((char*)Eh + off) = h;
            *(bf16x8*)((char*)El + off) = l;
        }
    }
    enorm[col] = s;
}

// ---------------- z_e -> flat fp32 A (out Q region) + swizzled (-2x) hi/lo ----
// Ah/Al image per 64-row block bn: [mi][ch][q][r16] 16B cells (32 KB/plane).
__global__ void vq_transpose_split(const float* __restrict__ ze, float* __restrict__ A,
                                   __bf16* __restrict__ Ah, __bf16* __restrict__ Al) {
    __shared__ float T[16 * 272];
    int tid = threadIdx.x;
    int m  = blockIdx.x & 15;
    int lt = blockIdx.x >> 4;
    int l0 = lt * 16;
#pragma unroll
    for (int it = 0; it < 4; ++it) {
        int p   = tid + it * 256;
        int b   = p >> 6;
        int clo = (p >> 2) & 15;
        int l4  = p & 3;
        const float* g = ze + (size_t)b * ZE_CL + (size_t)(m * 16 + clo) * 2048 + l0 + 4 * l4;
        float4 v = *(const float4*)g;
        int jp = 17 * clo + b;
        T[(4 * l4 + 0) * 272 + jp] = v.x;
        T[(4 * l4 + 1) * 272 + jp] = v.y;
        T[(4 * l4 + 2) * 272 + jp] = v.z;
        T[(4 * l4 + 3) * 272 + jp] = v.w;
    }
    __syncthreads();
#pragma unroll
    for (int it = 0; it < 4; ++it) {
        int p  = tid + it * 256;
        int ll = p >> 6;
        int c4 = p & 63;
        int j0 = 4 * c4;
        int base = ll * 272 + 17 * (j0 >> 4) + (j0 & 15);
        float4 v;
        v.x = T[base + 0]; v.y = T[base + 1]; v.z = T[base + 2]; v.w = T[base + 3];
        int n = (l0 + ll) * 16 + m;
        *(float4*)(A + (size_t)n * DD + j0) = v;
        if (Ah) {
            float a0 = -2.f * v.x, a1 = -2.f * v.y, a2 = -2.f * v.z, a3 = -2.f * v.w;
            bf16x4 h, l;
            h[0] = (__bf16)a0; l[0] = (__bf16)(a0 - (float)h[0]);
            h[1] = (__bf16)a1; l[1] = (__bf16)(a1 - (float)h[1]);
            h[2] = (__bf16)a2; l[2] = (__bf16)(a2 - (float)h[2]);
            h[3] = (__bf16)a3; l[3] = (__bf16)(a3 - (float)h[3]);
            int bn = n >> 6, mi = (n >> 4) & 3, r = n & 15;
            int ch = j0 >> 5, q = (j0 >> 3) & 3, hb = (j0 & 7) * 2;
            size_t off = (size_t)bn * 32768 + (size_t)((mi * 8 + ch) * 1024 + q * 256 + r * 16 + hb);
            *(bf16x4*)((char*)Ah + off) = h;
            *(bf16x4*)((char*)Al + off) = l;
        }
    }
}

// ---------------- MFMA distance + top-2 argmin + fused epilogue ----------------
// 512 blocks x 4 waves. Block: 64 rows x 2048 cols (8 nt-tiles of 256).
// Wave: 64 cols via 4x4 frags of mfma_f32_16x16x32_bf16. A frags stream
// global->VGPR (L2-hot, lane-linear); B chunk DMA'd to LDS (conflict-free b128).
__global__ __launch_bounds__(256, 2) void vq_main_mfma(
    const __bf16* __restrict__ Ah, const __bf16* __restrict__ Al,
    const __bf16* __restrict__ Eh, const __bf16* __restrict__ El,
    const float* __restrict__ enorm, const float* __restrict__ emb,
    float* out, int* __restrict__ rcount, int* __restrict__ rlist)
{
    __shared__ __align__(16) __bf16 sB[16384];   // 32 KB: hi [0,16K)B, lo [16K,32K)B
    __shared__ float sRv[256], sR2[256];
    __shared__ int   sRi[256];
    __shared__ int   sIdx[64], sFlag[64];
    __shared__ float wsum[4];

    const int tid  = threadIdx.x;
    const int wv   = tid >> 6;
    const int lane = tid & 63;
    const int l15  = lane & 15;
    const int quad = lane >> 4;
    const int n0   = blockIdx.x * 64;

    const char* AhB = (const char*)Ah + (size_t)blockIdx.x * 32768;
    const char* AlB = (const char*)Al + (size_t)blockIdx.x * 32768;

    float v1[16], v2[16]; int i1[16];
#pragma unroll
    for (int s = 0; s < 16; ++s) { v1[s] = 3.4e38f; v2[s] = 3.4e38f; i1[s] = 0; }

    for (int nt = 0; nt < 8; ++nt) {
        const char* EhT = (const char*)Eh + (size_t)nt * (8 * 16384);
        const char* ElT = (const char*)El + (size_t)nt * (8 * 16384);
        f32x4 acc[4][4];
#pragma unroll
        for (int a = 0; a < 4; ++a)
#pragma unroll
            for (int b = 0; b < 4; ++b) acc[a][b] = (f32x4){0.f, 0.f, 0.f, 0.f};

        for (int ch = 0; ch < 8; ++ch) {
            __syncthreads();   // prior B reads complete before DMA overwrites
            {
                const char* srcH = EhT + ch * 16384;
                const char* srcL = ElT + ch * 16384;
#pragma unroll
                for (int it = 0; it < 4; ++it) {
                    int off = (it * 4 + wv) * 1024;    // wave-uniform LDS base
                    gld_lds16(srcH + off + lane * 16, (char*)sB + off);
                    gld_lds16(srcL + off + lane * 16, (char*)sB + 16384 + off);
                }
            }
            bf16x8 ah[4], al[4];
#pragma unroll
            for (int mi = 0; mi < 4; ++mi) {
                size_t off = (size_t)((mi * 8 + ch) * 1024 + quad * 256 + l15 * 16);
                ah[mi] = *(const bf16x8*)(AhB + off);
                al[mi] = *(const bf16x8*)(AlB + off);
            }
            __syncthreads();   // drains DMA (vmcnt 0) + A-frag loads
            bf16x8 bh[4], bl[4];
#pragma unroll
            for (int nj = 0; nj < 4; ++nj) {
                int boff = (wv * 4 + nj) * 1024 + quad * 256 + l15 * 16;
                bh[nj] = *(const bf16x8*)((const char*)sB + boff);
                bl[nj] = *(const bf16x8*)((const char*)sB + 16384 + boff);
            }
#pragma unroll
            for (int mi = 0; mi < 4; ++mi)
#pragma unroll
                for (int nj = 0; nj < 4; ++nj)
                    acc[mi][nj] = __builtin_amdgcn_mfma_f32_16x16x32_bf16(ah[mi], bh[nj], acc[mi][nj], 0, 0, 0);
#pragma unroll
            for (int mi = 0; mi < 4; ++mi)
#pragma unroll
                for (int nj = 0; nj < 4; ++nj)
                    acc[mi][nj] = __builtin_amdgcn_mfma_f32_16x16x32_bf16(ah[mi], bl[nj], acc[mi][nj], 0, 0, 0);
#pragma unroll
            for (int mi = 0; mi < 4; ++mi)
#pragma unroll
                for (int nj = 0; nj < 4; ++nj)
                    acc[mi][nj] = __builtin_amdgcn_mfma_f32_16x16x32_bf16(al[mi], bh[nj], acc[mi][nj], 0, 0, 0);
        }
        // fold N-tile into running top-2 (branchless)
#pragma unroll
        for (int nj = 0; nj < 4; ++nj) {
            int k = nt * 256 + wv * 64 + nj * 16 + l15;
            float en = enorm[k];
#pragma unroll
            for (int mi = 0; mi < 4; ++mi)
#pragma unroll
                for (int r = 0; r < 4; ++r) {
                    float d = acc[mi][nj][r] + en;
                    int slot = mi * 4 + r;
                    float nv2 = fminf(v2[slot], fmaxf(v1[slot], d));
                    if (d < v1[slot]) i1[slot] = k;
                    v1[slot] = fminf(v1[slot], d);
                    v2[slot] = nv2;
                }
        }
    }

    // cross-lane top-2 merge over 16 lanes (rows fixed per quad)
#pragma unroll
    for (int slot = 0; slot < 16; ++slot) {
        float a1 = v1[slot], a2 = v2[slot];
        int ai = i1[slot];
#pragma unroll
        for (int m = 1; m < 16; m <<= 1) {
            float b1 = __shfl_xor(a1, m, 64);
            float b2 = __shfl_xor(a2, m, 64);
            int bi = __shfl_xor(ai, m, 64);
            float n2 = fminf(fminf(a2, b2), fmaxf(a1, b1));
            if (b1 < a1) ai = bi;
            a1 = fminf(a1, b1);
            a2 = n2;
        }
        if (l15 == 0) {
            int row = (slot >> 2) * 16 + quad * 4 + (slot & 3);
            sRv[row * 4 + wv] = a1;
            sR2[row * 4 + wv] = a2;
            sRi[row * 4 + wv] = ai;
        }
    }
    __syncthreads();
    if (tid < 64) {
        float a1 = sRv[tid * 4], a2 = sR2[tid * 4];
        int ai = sRi[tid * 4];
#pragma unroll
        for (int w2 = 1; w2 < 4; ++w2) {
            float b1 = sRv[tid * 4 + w2], b2 = sR2[tid * 4 + w2];
            int bi = sRi[tid * 4 + w2];
            float n2 = fminf(fminf(a2, b2), fmaxf(a1, b1));
            if (b1 < a1) ai = bi;
            a1 = fminf(a1, b1);
            a2 = n2;
        }
        int fg = (a2 - a1 < D2) ? 1 : 0;
        sIdx[tid] = ai;
        sFlag[tid] = fg;
        out[IDX_OFF + n0 + tid] = (float)ai;
        if (fg) { int p = atomicAdd(rcount, 1); rlist[p] = n0 + tid; }
    }
    __syncthreads();

    // fused epilogue: quantize + loss for non-flagged rows (x fp32 still in out)
    float lacc = 0.f;
#pragma unroll
    for (int it = 0; it < 16; ++it) {
        int p = tid + it * 256;
        int r = p >> 6;             // whole wave shares a row -> uniform branch
        int c4 = p & 63;
        if (!sFlag[r]) {
            int k = sIdx[r];
            size_t off = (size_t)(n0 + r) * DD + 4 * c4;
            float4 q = *(const float4*)(emb + (size_t)k * DD + 4 * c4);
            float4 a = *(const float4*)(out + off);
            float dx = q.x - a.x, dy = q.y - a.y, dz = q.z - a.z, dw = q.w - a.w;
            lacc += dx * dx + dy * dy + dz * dz + dw * dw;
            *(float4*)(out + off) = q;
        }
    }
#pragma unroll
    for (int off = 32; off > 0; off >>= 1) lacc += __shfl_down(lacc, off, 64);
    if ((tid & 63) == 0) wsum[tid >> 6] = lacc;
    __syncthreads();
    if (tid == 0) {
        float bs = wsum[0] + wsum[1] + wsum[2] + wsum[3];
        atomicAdd(out + LOSS_OFF, bs * (1.25f / 8388608.0f));
    }
}

// ---------------- exact fp32 finalize of flagged rows ----------------
__global__ void vq_rescore(const float* __restrict__ emb, const float* __restrict__ enorm,
                           float* out, const int* __restrict__ rcount,
                           const int* __restrict__ rlist) {
    __shared__ float sX[256];
    __shared__ float sV[256];
    __shared__ int   sK[256];
    __shared__ float sP[256];
    int cnt = *rcount;
    int tid = threadIdx.x;
    for (int li = blockIdx.x; li < cnt; li += gridDim.x) {
        int row = rlist[li];
        __syncthreads();
        sX[tid] = out[(size_t)row * DD + tid];   // fp32 x (main skipped this row)
        __syncthreads();
        float bv = 3.4e38f; int bk = 0;
        for (int jj = 0; jj < 8; ++jj) {
            int k = jj * 256 + tid;   // ascending per thread: '<' keeps first
            const float4* e4 = (const float4*)(emb + (size_t)k * DD);
            float dot = 0.f;
#pragma unroll 8
            for (int d4 = 0; d4 < 64; ++d4) {
                float4 e = e4[d4];
                float4 x = *(const float4*)(sX + d4 * 4);
                dot += x.x * e.x + x.y * e.y + x.z * e.z + x.w * e.w;
            }
            float s = enorm[k] - 2.f * dot;
            if (s < bv) { bv = s; bk = k; }
        }
        sV[tid] = bv; sK[tid] = bk;
        __syncthreads();
#pragma unroll
        for (int s = 128; s > 0; s >>= 1) {
            if (tid < s) {
                float vo = sV[tid + s]; int ko = sK[tid + s];
                if (vo < sV[tid] || (vo == sV[tid] && ko < sK[tid])) { sV[tid] = vo; sK[tid] = ko; }
            }
            __syncthreads();
        }
        int k = sK[0];
        float x = sX[tid];
        float q = emb[(size_t)k * DD + tid];
        out[(size_t)row * DD + tid] = q;
        float d = q - x;
        sP[tid] = d * d;
        __syncthreads();
#pragma unroll
        for (int s = 128; s > 0; s >>= 1) {
            if (tid < s) sP[tid] += sP[tid + s];
            __syncthreads();
        }
        if (tid == 0) {
            out[IDX_OFF + row] = (float)k;
            atomicAdd(out + LOSS_OFF, sP[0] * (1.25f / 8388608.0f));
        }
    }
}

// ---------------- fallback fp32 main (only if ws too small) ----------------
__global__ __launch_bounds__(256, 2) void vq_main_f32(const float* __restrict__ emb,
                                                      const float* __restrict__ enorm,
                                                      float* out) {
    const int SA = 68, SE = 68;
    __shared__ float smem[64 * 68 + 64 * 68];
    __shared__ int   sIdx[64];
    __shared__ float wsum[4];
    float* sA = smem;
    float* sEb = smem + 64 * SA;
    float* redv = sEb;
    int*   redi = (int*)(sEb + 64 * 16);
    int tid = threadIdx.x;
    int n0 = blockIdx.x * 64;
    int rg = tid & 15;
    int kg = tid >> 4;
    float minv[4]; int mini[4];
#pragma unroll
    for (int i = 0; i < 4; ++i) { minv[i] = 3.4e38f; mini[i] = 0; }
    const float* A = out;
    for (int kt = 0; kt < KC / 64; ++kt) {
        int k0 = kt * 64;
        float acc[4][4];
#pragma unroll
        for (int i = 0; i < 4; ++i)
#pragma unroll
            for (int j = 0; j < 4; ++j) acc[i][j] = 0.f;
        for (int dc = 0; dc < 4; ++dc) {
            int d0 = dc * 64;
            __syncthreads();
#pragma unroll
            for (int it = 0; it < 4; ++it) {
                int p = tid + it * 256, r = p >> 4, c4 = p & 15;
                *(float4*)(sA + r * SA + 4 * c4) =
                    *(const float4*)(A + (size_t)(n0 + r) * DD + d0 + 4 * c4);
            }
#pragma unroll
            for (int it = 0; it < 4; ++it) {
                int p = tid + it * 256, r = p >> 4, c4 = p & 15;
                *(float4*)(sEb + r * SE + 4 * c4) =
                    *(const float4*)(emb + (size_t)(k0 + r) * DD + d0 + 4 * c4);
            }
            __syncthreads();
#pragma unroll
            for (int d4 = 0; d4 < 16; ++d4) {
                float4 av[4], ev[4];
#pragma unroll
                for (int i = 0; i < 4; ++i) av[i] = *(const float4*)(sA + (rg + 16 * i) * SA + 4 * d4);
#pragma unroll
                for (int j = 0; j < 4; ++j) ev[j] = *(const float4*)(sEb + (kg + 16 * j) * SE + 4 * d4);
#pragma unroll
                for (int i = 0; i < 4; ++i)
#pragma unroll
                    for (int j = 0; j < 4; ++j)
                        acc[i][j] += av[i].x * ev[j].x + av[i].y * ev[j].y +
                                     av[i].z * ev[j].z + av[i].w * ev[j].w;
            }
        }
#pragma unroll
        for (int j = 0; j < 4; ++j) {
            int k = k0 + kg + 16 * j;
            float en = enorm[k];
#pragma unroll
            for (int i = 0; i < 4; ++i) {
                float s = en - 2.f * acc[i][j];
                if (s < minv[i]) { minv[i] = s; mini[i] = k; }
            }
        }
    }
    __syncthreads();
#pragma unroll
    for (int i = 0; i < 4; ++i) {
        int r = rg + 16 * i;
        redv[r * 16 + kg] = minv[i];
        redi[r * 16 + kg] = mini[i];
    }
    __syncthreads();
    if (tid < 64) {
        float bv = redv[tid * 16]; int bi = redi[tid * 16];
        for (int t = 1; t < 16; ++t) {
            float v = redv[tid * 16 + t]; int ii = redi[tid * 16 + t];
            if (v < bv || (v == bv && ii < bi)) { bv = v; bi = ii; }
        }
        sIdx[tid] = bi;
        out[IDX_OFF + n0 + tid] = (float)bi;
    }
    __syncthreads();
    float lacc = 0.f;
#pragma unroll
    for (int it = 0; it < 16; ++it) {
        int p = tid + it * 256, r = p >> 6, c4 = p & 63;
        int k = sIdx[r];
        size_t off = (size_t)(n0 + r) * DD + 4 * c4;
        float4 q = *(const float4*)(emb + (size_t)k * DD + 4 * c4);
        float4 a = *(const float4*)(out + off);
        float dx = q.x - a.x, dy = q.y - a.y, dz = q.z - a.z, dw = q.w - a.w;
        lacc += dx * dx + dy * dy + dz * dz + dw * dw;
        *(float4*)(out + off) = q;
    }
#pragma unroll
    for (int off = 32; off > 0; off >>= 1) lacc += __shfl_down(lacc, off, 64);
    if ((tid & 63) == 0) wsum[tid >> 6] = lacc;
    __syncthreads();
    if (tid == 0) {
        float bs = wsum[0] + wsum[1] + wsum[2] + wsum[3];
        atomicAdd(out + LOSS_OFF, bs * (1.25f / 8388608.0f));
    }
}

extern "C" void kernel_launch(void* const* d_in, const int* in_sizes, int n_in,
                              void* d_out, int out_size, void* d_ws, size_t ws_size,
                              hipStream_t stream) {
    (void)in_sizes; (void)n_in; (void)out_size;
    const float* ze  = (const float*)d_in[0];
    const float* emb = (const float*)d_in[1];
    float* out = (float*)d_out;
    char*  ws  = (char*)d_ws;
    float* enorm = (float*)(ws + EN_OFF);

    hipMemsetAsync((char*)d_out + (size_t)LOSS_OFF * 4, 0, 4, stream);

    if (ws_size >= (size_t)WS_NEED) {
        __bf16* Eh = (__bf16*)(ws + EH_OFF);
        __bf16* El = (__bf16*)(ws + EL_OFF);
        __bf16* Ah = (__bf16*)(ws + AH_OFF);
        __bf16* Al = (__bf16*)(ws + AL_OFF);
        int* rcount = (int*)(ws + CNT_OFF);
        int* rlist  = (int*)(ws + LST_OFF);
        hipMemsetAsync(ws + CNT_OFF, 0, 16, stream);
        vq_prep_emb<<<8, 256, 0, stream>>>(emb, enorm, Eh, El);
        vq_transpose_split<<<2048, 256, 0, stream>>>(ze, out, Ah, Al);
        vq_main_mfma<<<NROWS / 64, 256, 0, stream>>>(Ah, Al, Eh, El, enorm, emb, out, rcount, rlist);
        vq_rescore<<<64, 256, 0, stream>>>(emb, enorm, out, rcount, rlist);
    } else {
        // fallback: fp32 path (slow but correct)
        {
            // enorm via prep-less kernel: reuse vq_prep_emb minus swizzle is not
            // available; compute enorm with a tiny dedicated launch
        }
        vq_prep_emb<<<8, 256, 0, stream>>>(emb, enorm, (__bf16*)(ws + EH_OFF), (__bf16*)(ws + EH_OFF));
        vq_transpose_split<<<2048, 256, 0, stream>>>(ze, out, (__bf16*)0, (__bf16*)0);
        vq_main_f32<<<NROWS / 64, 256, 0, stream>>>(emb, enorm, out);
    }
}